// Round 1
// baseline (633.901 us; speedup 1.0000x reference)
//
#include <hip/hip_runtime.h>

// Problem dims (fixed by reference)
#define Bq 32
#define Sq 64
#define Iq 256
#define Hq 256
#define Oq 128
#define Fq 512          // Iq + Hq
#define CHUNK 32        // h-rows per workgroup
#define WPB 8           // workgroups per batch (CHUNK*WPB == Hq)
#define NT 512          // threads per workgroup (8 waves)
#define CPT 32          // columns per thread (16 col-groups * 32 rows == NT)

// Persistent recurrence kernel: one wg owns a (32 x 512) slab of f for one
// batch, f/w/lambda/gamma live in registers for all 64 steps. Cross-wg h
// exchange via double-buffered global buffer + batch-local atomic barrier.
__global__ __launch_bounds__(NT, 2) void stpn_main(
    const float* __restrict__ x,     // (B,S,I)
    const float* __restrict__ w,     // (H,F)
    const float* __restrict__ wl,    // (H,F)
    const float* __restrict__ wgm,   // (H,F)
    const float* __restrict__ bias,  // (H)
    float* __restrict__ out,         // [tag(B*O) | h_fin(B*H) | f_fin(B*H*F)]
    float* __restrict__ ws)          // [cnt: B ctrs @128B stride (4KB)][hbuf: 2*B*H floats]
{
    const int blk   = blockIdx.x;
    const int b     = blk % Bq;       // same-batch wgs land on same XCD (round-robin)
    const int chunk = blk / Bq;       // 0..7
    const int h0    = chunk * CHUNK;
    const int tid   = threadIdx.x;
    const int r     = tid & 31;       // row within chunk (lanes 0..31 share col-group)
    const int cg    = tid >> 5;       // col group 0..15
    const int c0    = cg * CPT;

    unsigned int* cnt = (unsigned int*)ws + b * 32;   // 128B-separated counters
    float* hbuf = ws + 1024;                          // 2 * B * H floats

    __shared__ float ti[Fq];              // total_input for this batch/step
    __shared__ float red_pre[16][32];
    __shared__ float red_nsq[16][32];
    __shared__ float sh_hn[32];
    __shared__ float sh_inv[32];

    // Static per-element params + fast-weight state, all in registers.
    float fw[CPT], fl[CPT], fg[CPT], ff[CPT];
    {
        const float4* w4 = (const float4*)(w   + (size_t)(h0 + r) * Fq + c0);
        const float4* l4 = (const float4*)(wl  + (size_t)(h0 + r) * Fq + c0);
        const float4* g4 = (const float4*)(wgm + (size_t)(h0 + r) * Fq + c0);
#pragma unroll
        for (int j = 0; j < CPT / 4; ++j) {
            float4 a = w4[j], bb = l4[j], c = g4[j];
            fw[4*j+0] = a.x;  fw[4*j+1] = a.y;  fw[4*j+2] = a.z;  fw[4*j+3] = a.w;
            fl[4*j+0] = bb.x; fl[4*j+1] = bb.y; fl[4*j+2] = bb.z; fl[4*j+3] = bb.w;
            fg[4*j+0] = c.x;  fg[4*j+1] = c.y;  fg[4*j+2] = c.z;  fg[4*j+3] = c.w;
        }
    }
#pragma unroll
    for (int j = 0; j < CPT; ++j) ff[j] = 0.f;

    const float b_r = (tid < 32) ? bias[h0 + tid] : 0.f;

    for (int t = 0; t < Sq; ++t) {
        // Wait until all 8 wgs of this batch finished step t-1 (their h is published).
        if (t > 0 && tid == 0) {
            const unsigned target = (unsigned)(WPB * t);
            while (__hip_atomic_load(cnt, __ATOMIC_ACQUIRE, __HIP_MEMORY_SCOPE_AGENT) < target)
                __builtin_amdgcn_s_sleep(1);
        }
        __syncthreads();

        // Build total_input = [x_t | h_{t-1}] in LDS.
        if (tid < Iq) {
            ti[tid] = x[(size_t)b * Sq * Iq + (size_t)t * Iq + tid];
        } else {
            const int hh = tid - Iq;
            float hv = 0.f;
            if (t > 0)
                hv = __hip_atomic_load(&hbuf[((t - 1) & 1) * Bq * Hq + b * Hq + hh],
                                       __ATOMIC_RELAXED, __HIP_MEMORY_SCOPE_AGENT);
            ti[Iq + hh] = hv;
        }
        __syncthreads();

        // Per-thread partial pre / norm^2 over this thread's 32 columns.
        float pre = 0.f, nsq = 0.f;
#pragma unroll
        for (int j = 0; j < CPT; ++j) {
            const float tw = fw[j] + ff[j];
            pre = fmaf(ti[c0 + j], tw, pre);
            nsq = fmaf(tw, tw, nsq);
        }
        red_pre[cg][r] = pre;
        red_nsq[cg][r] = nsq;
        __syncthreads();

        // Row reduction + activation by threads 0..31.
        if (tid < 32) {
            float p = 0.f, n = 0.f;
#pragma unroll
            for (int g = 0; g < 16; ++g) { p += red_pre[g][tid]; n += red_nsq[g][tid]; }
            const float norm = sqrtf(n) + 1e-16f;
            const float inv  = 1.f / norm;
            const float hn   = tanhf(p * inv + b_r);
            sh_hn[tid]  = hn;
            sh_inv[tid] = inv;
            if (t < Sq - 1) {
                __hip_atomic_store(&hbuf[(t & 1) * Bq * Hq + b * Hq + h0 + tid], hn,
                                   __ATOMIC_RELAXED, __HIP_MEMORY_SCOPE_AGENT);
                __threadfence();
            } else {
                out[Bq * Oq + b * Hq + h0 + tid] = hn;  // h_fin
            }
        }
        __syncthreads();

        // Publish arrival for this step (after h stores are fenced), then the
        // f-update overlaps with other wgs picking up our h.
        if (t < Sq - 1 && tid == 0)
            __hip_atomic_fetch_add(cnt, 1u, __ATOMIC_RELEASE, __HIP_MEMORY_SCOPE_AGENT);

        {
            const float hn  = sh_hn[r];
            const float inv = sh_inv[r];
#pragma unroll
            for (int j = 0; j < CPT; ++j)
                ff[j] = fmaf(fl[j], ff[j] * inv, fg[j] * (hn * ti[c0 + j]));
        }
    }

    // Write f_fin: each thread owns a 128B-contiguous span of one row.
    float* fo = out + Bq * Oq + Bq * Hq + (size_t)b * Hq * Fq + (size_t)(h0 + r) * Fq + c0;
#pragma unroll
    for (int j = 0; j < CPT / 4; ++j) {
        float4 v;
        v.x = ff[4*j+0]; v.y = ff[4*j+1]; v.z = ff[4*j+2]; v.w = ff[4*j+3];
        ((float4*)fo)[j] = v;
    }
}

// tag_space = h_fin @ out_w.T + out_b  (tiny: 32x128x256)
__global__ void stpn_tag(const float* __restrict__ ow, const float* __restrict__ ob,
                         float* out)
{
    const int b = blockIdx.x;    // B
    const int o = threadIdx.x;   // O
    const float* hf = out + Bq * Oq + b * Hq;
    const float* wr = ow + (size_t)o * Hq;
    float acc = ob[o];
#pragma unroll 8
    for (int h = 0; h < Hq; ++h) acc = fmaf(hf[h], wr[h], acc);
    out[b * Oq + o] = acc;
}

extern "C" void kernel_launch(void* const* d_in, const int* in_sizes, int n_in,
                              void* d_out, int out_size, void* d_ws, size_t ws_size,
                              hipStream_t stream)
{
    const float* x    = (const float*)d_in[0];
    const float* w    = (const float*)d_in[1];
    const float* wl   = (const float*)d_in[2];
    const float* wgm  = (const float*)d_in[3];
    const float* bias = (const float*)d_in[4];
    const float* ow   = (const float*)d_in[5];
    const float* ob   = (const float*)d_in[6];
    float* out = (float*)d_out;
    float* ws  = (float*)d_ws;

    // Zero the batch barrier counters (first 4KB of workspace). Graph-capture safe.
    hipMemsetAsync(d_ws, 0, 4096, stream);

    stpn_main<<<Bq * WPB, NT, 0, stream>>>(x, w, wl, wgm, bias, out, ws);
    stpn_tag<<<Bq, Oq, 0, stream>>>(ow, ob, out);
}

// Round 2
// 160.981 us; speedup vs baseline: 3.9377x; 3.9377x over previous
//
#include <hip/hip_runtime.h>

// Problem dims (fixed by reference)
#define Bq 32
#define Sq 64
#define Iq 256
#define Hq 256
#define Oq 128
#define Fq 512          // Iq + Hq
#define WPB 8           // workgroups per batch (8 * 32 rows == Hq)
#define NT 512          // threads per workgroup (8 waves)

// One wg owns a (32 x 512) slab of f for one batch; w/lambda/gamma/f live in
// registers (unified VGPR/AGPR file) for all 64 steps.
// Thread mapping: row r = tid>>4 (32 rows), 16 lanes per row, each lane owns
// 8 float4 column chunks at col = 4*(tid&15) + 64*j. Row reduction is a
// 16-lane shuffle butterfly (no LDS, no extra barrier).
// Cross-wg h exchange: 64-bit relaxed agent atomics packing (tag<<32|bits(h)).
// No fences, no buffer_inv/wbl2 on the critical path. Double-buffered by step
// parity; tag-exact match gives implicit back-pressure (see proof in session
// notes: overwriting parity p at step t+1 requires having seen all tags t+1,
// which requires all peers to have finished their step-t reads of parity p).
__global__ __launch_bounds__(NT, 2) void stpn_main(
    const float* __restrict__ x,     // (B,S,I)
    const float* __restrict__ w,     // (H,F)
    const float* __restrict__ wl,    // (H,F)
    const float* __restrict__ wgm,   // (H,F)
    const float* __restrict__ bias,  // (H)
    float* __restrict__ out,         // [tag(B*O) | h_fin(B*H) | f_fin(B*H*F)]
    unsigned long long* __restrict__ hb) // [2][B][H] (tag,val) slots, zeroed
{
    const int blk   = blockIdx.x;
    const int b     = blk & 31;       // same-batch wgs round-robin onto XCDs
    const int chunk = blk >> 5;       // 0..7
    const int h0    = chunk * 32;
    const int tid   = threadIdx.x;
    const int lr    = tid & 15;       // lane within row group
    const int r     = tid >> 4;       // row 0..31
    const int row   = h0 + r;

    __shared__ float ti[2][Fq];       // double-buffered total_input

    // Static per-element params + fast-weight state, registers/AGPRs.
    float fw[32], fl[32], fg[32], ff[32];
    const size_t rowoff = (size_t)row * Fq;
#pragma unroll
    for (int j = 0; j < 8; ++j) {
        const int c = 4 * lr + 64 * j;
        const float4 a = *(const float4*)(w   + rowoff + c);
        const float4 l = *(const float4*)(wl  + rowoff + c);
        const float4 g = *(const float4*)(wgm + rowoff + c);
        fw[4*j+0]=a.x; fw[4*j+1]=a.y; fw[4*j+2]=a.z; fw[4*j+3]=a.w;
        fl[4*j+0]=l.x; fl[4*j+1]=l.y; fl[4*j+2]=l.z; fl[4*j+3]=l.w;
        fg[4*j+0]=g.x; fg[4*j+1]=g.y; fg[4*j+2]=g.z; fg[4*j+3]=g.w;
    }
#pragma unroll
    for (int j = 0; j < 32; ++j) ff[j] = 0.f;

    const float brow = bias[row];
    const float* xb = x + (size_t)b * Sq * Iq;

    for (int t = 0; t < Sq; ++t) {
        const int p = t & 1;
        // Build total_input = [x_t | h_{t-1}] in LDS parity p.
        if (tid < Iq) {
            ti[p][tid] = xb[(size_t)t * Iq + tid];
        } else {
            const int hh = tid - Iq;
            float hv = 0.f;
            if (t > 0) {
                unsigned long long* slot =
                    hb + (size_t)((t - 1) & 1) * Bq * Hq + (size_t)b * Hq + hh;
                unsigned long long v;
                for (;;) {
                    v = __hip_atomic_load(slot, __ATOMIC_RELAXED,
                                          __HIP_MEMORY_SCOPE_AGENT);
                    if ((unsigned)(v >> 32) == (unsigned)t) break;
                }
                hv = __uint_as_float((unsigned)(v & 0xffffffffu));
            }
            ti[p][Iq + hh] = hv;
        }
        __syncthreads();   // the ONLY barrier per step (ti dbuf handles WAR)

        // Per-lane partials over 8 float4 column chunks.
        float pre = 0.f, nsq = 0.f;
#pragma unroll
        for (int j = 0; j < 8; ++j) {
            const float4 tv = *(const float4*)&ti[p][4 * lr + 64 * j];
            float tw;
            tw = fw[4*j+0] + ff[4*j+0]; pre = fmaf(tv.x, tw, pre); nsq = fmaf(tw, tw, nsq);
            tw = fw[4*j+1] + ff[4*j+1]; pre = fmaf(tv.y, tw, pre); nsq = fmaf(tw, tw, nsq);
            tw = fw[4*j+2] + ff[4*j+2]; pre = fmaf(tv.z, tw, pre); nsq = fmaf(tw, tw, nsq);
            tw = fw[4*j+3] + ff[4*j+3]; pre = fmaf(tv.w, tw, pre); nsq = fmaf(tw, tw, nsq);
        }
        // Butterfly across the 16 lanes of this row: all lanes get full sums.
#pragma unroll
        for (int m = 1; m < 16; m <<= 1) {
            pre += __shfl_xor(pre, m, 16);
            nsq += __shfl_xor(nsq, m, 16);
        }
        const float inv = 1.f / (sqrtf(nsq) + 1e-16f);
        const float hn  = tanhf(fmaf(pre, inv, brow));

        // Publish this row's h (each wave publishes as soon as ITS rows are done).
        if (lr == 0) {
            if (t < Sq - 1) {
                const unsigned long long pk =
                    ((unsigned long long)(unsigned)(t + 1) << 32) |
                    (unsigned long long)__float_as_uint(hn);
                __hip_atomic_store(
                    hb + (size_t)(t & 1) * Bq * Hq + (size_t)b * Hq + row, pk,
                    __ATOMIC_RELAXED, __HIP_MEMORY_SCOPE_AGENT);
            } else {
                out[Bq * Oq + (size_t)b * Hq + row] = hn;   // h_fin
            }
        }

        // f update (per-lane; hn/inv already in every lane).
#pragma unroll
        for (int j = 0; j < 8; ++j) {
            const float4 tv = *(const float4*)&ti[p][4 * lr + 64 * j];
            ff[4*j+0] = fmaf(fl[4*j+0], ff[4*j+0] * inv, fg[4*j+0] * (hn * tv.x));
            ff[4*j+1] = fmaf(fl[4*j+1], ff[4*j+1] * inv, fg[4*j+1] * (hn * tv.y));
            ff[4*j+2] = fmaf(fl[4*j+2], ff[4*j+2] * inv, fg[4*j+2] * (hn * tv.z));
            ff[4*j+3] = fmaf(fl[4*j+3], ff[4*j+3] * inv, fg[4*j+3] * (hn * tv.w));
        }
    }

    // Write f_fin: 16 lanes x float4 = 256B contiguous per row chunk.
    float* fo = out + Bq * Oq + Bq * Hq + (size_t)b * Hq * Fq + rowoff;
#pragma unroll
    for (int j = 0; j < 8; ++j) {
        const int c = 4 * lr + 64 * j;
        float4 v;
        v.x = ff[4*j+0]; v.y = ff[4*j+1]; v.z = ff[4*j+2]; v.w = ff[4*j+3];
        *(float4*)(fo + c) = v;
    }
}

// tag_space = h_fin @ out_w.T + out_b  (tiny: 32x128x256)
__global__ void stpn_tag(const float* __restrict__ ow, const float* __restrict__ ob,
                         float* out)
{
    const int b = blockIdx.x;    // B
    const int o = threadIdx.x;   // O
    const float* hf = out + Bq * Oq + (size_t)b * Hq;
    const float* wr = ow + (size_t)o * Hq;
    float acc = ob[o];
#pragma unroll 8
    for (int h = 0; h < Hq; ++h) acc = fmaf(hf[h], wr[h], acc);
    out[b * Oq + o] = acc;
}

extern "C" void kernel_launch(void* const* d_in, const int* in_sizes, int n_in,
                              void* d_out, int out_size, void* d_ws, size_t ws_size,
                              hipStream_t stream)
{
    const float* x    = (const float*)d_in[0];
    const float* w    = (const float*)d_in[1];
    const float* wl   = (const float*)d_in[2];
    const float* wgm  = (const float*)d_in[3];
    const float* bias = (const float*)d_in[4];
    const float* ow   = (const float*)d_in[5];
    const float* ob   = (const float*)d_in[6];
    float* out = (float*)d_out;

    // Zero the (tag,val) h-exchange slots: 2 * B * H * 8 bytes = 128 KB.
    hipMemsetAsync(d_ws, 0, 2 * Bq * Hq * sizeof(unsigned long long), stream);

    stpn_main<<<Bq * WPB, NT, 0, stream>>>(x, w, wl, wgm, bias, out,
                                           (unsigned long long*)d_ws);
    stpn_tag<<<Bq, Oq, 0, stream>>>(ow, ob, out);
}